// Round 4
// baseline (3981.156 us; speedup 1.0000x reference)
//
#include <hip/hip_runtime.h>
#include <hip/hip_bf16.h>
#include <math.h>

// ---------------------------------------------------------------------------
// LSTM text classifier forward, MI355X/gfx950.  Round 4.
//
// R3 post-mortem: asm pin failed again (VGPR=124 < 128 needed); U streamed
// from L2 inside the loop, and 4 waves couldn't hide the dependent-load
// latency (4.6us/step). Lesson: the allocator will NOT hold U in registers.
//
// R4: U lives in LDS (the compiler's happy path: ds_read_b128 -> MFMA).
//   32 blocks = 4 batch-groups x 8 unit-slices (32 units).
//   Per block: U-slice 64 KB in LDS (loaded once), h double-buffered in LDS.
//   4 waves: w0,w1 compute (1 unit-tile each, all 4 gates, 32 MFMAs/step);
//            w2,w3 comm (spin + pull 7 sibling h-slices from L3).
//   Sync: per-(t,group,slice) counter, target 2 (one release fetch_add per
//   producing wave after its atomic dword stores) -- fixes R3's early-flag
//   race. Data slots double-buffered by t&1; counters unique per t -> no ABA.
//   One __syncthreads per step (h_lds double buffer).
//
// MFMA 16x16x32 bf16 layouts (m89/m91):
//   A[m][k]: m=lane&15, k=(lane>>4)*8+j      B[k][n]: n=lane&15, same k
//   C/D:     col=lane&15, row=(lane>>4)*4+reg
// ---------------------------------------------------------------------------

typedef __bf16 bf16_t;
typedef bf16_t bf16x8 __attribute__((ext_vector_type(8)));
typedef bf16_t bf16x4 __attribute__((ext_vector_type(4)));
typedef float  f32x4  __attribute__((ext_vector_type(4)));

#define T_SZ 512
#define HID 256
#define G4 1024
#define NCLS 20

// workspace layout (bytes)
#define WS_UPACK 0u
#define WS_WPACK (512u * 1024u)
#define WS_HFIN  (1024u * 1024u)                  // 64 KB
#define WS_CNT   (1024u * 1024u + 64u * 1024u)    // 64 KB (512*4*8 uints)
#define WS_HEXCH (1024u * 1024u + 128u * 1024u)   // 64 KB (2*4*8*256 dwords)
#define WS_XZ    (2u * 1024u * 1024u)             // 64 MB
// total: 66 MB

// ---------------------------------------------------------------------------
// Pack W and U (f32 [256][1024]) into bf16 B-fragment order:
// frag f = (ntile*8 + kstep)*64 + lane ; element j=0..7
// value = M[kstep*32 + (lane>>4)*8 + j][ntile*16 + (lane&15)]
// ---------------------------------------------------------------------------
__global__ void pack_weights(const float* __restrict__ W, const float* __restrict__ U,
                             bf16_t* __restrict__ Wp, bf16_t* __restrict__ Up) {
    int tid  = blockIdx.x * blockDim.x + threadIdx.x;   // 0..262143
    int j    = tid & 7;
    int lane = (tid >> 3) & 63;
    int ks   = (tid >> 9) & 7;
    int nt   = tid >> 12;
    int row  = ks * 32 + ((lane >> 4) << 3) + j;
    int col  = nt * 16 + (lane & 15);
    Wp[tid] = (bf16_t)W[row * G4 + col];
    Up[tid] = (bf16_t)U[row * G4 + col];
}

// ---------------------------------------------------------------------------
// Phase A: xz = emb[x] @ W + bias, stored bf16 in C-fragment order:
//   xz2[((t*4 + bchunk)*64 + ntile)*64 + lane] = bf16x4 {r=0..3}
// value[r] = z[batch = bchunk*16 + (lane>>4)*4 + r][col = ntile*16 + (lane&15)]
// ---------------------------------------------------------------------------
__global__ __launch_bounds__(256) void xz_gemm(const int* __restrict__ x,
                                               const float* __restrict__ emb,
                                               const bf16_t* __restrict__ Wp,
                                               const float* __restrict__ bias,
                                               bf16x4* __restrict__ xz2) {
    int nb   = blockIdx.x & 7;
    int t    = blockIdx.x >> 3;
    int w    = threadIdx.x >> 6;
    int lane = threadIdx.x & 63;
    int l15  = lane & 15;
    int quad = lane >> 4;

    int b_row = w * 16 + l15;
    int tok   = x[b_row * T_SZ + t];
    const float* erow = emb + (size_t)tok * 256;

    bf16x8 afrag[8];
#pragma unroll
    for (int ks = 0; ks < 8; ks++) {
        const float4* p = (const float4*)(erow + ks * 32 + quad * 8);
        float4 v0 = p[0], v1 = p[1];
        bf16x8 a;
        a[0] = (bf16_t)v0.x; a[1] = (bf16_t)v0.y; a[2] = (bf16_t)v0.z; a[3] = (bf16_t)v0.w;
        a[4] = (bf16_t)v1.x; a[5] = (bf16_t)v1.y; a[6] = (bf16_t)v1.z; a[7] = (bf16_t)v1.w;
        afrag[ks] = a;
    }

    const bf16x8* Wf = (const bf16x8*)Wp;

#pragma unroll
    for (int nt = 0; nt < 8; nt++) {
        int ntg = nb * 8 + nt;
        float bv = bias[ntg * 16 + l15];
        f32x4 acc = {bv, bv, bv, bv};
        const bf16x8* bp = Wf + (size_t)(ntg * 8) * 64 + lane;
#pragma unroll
        for (int ks = 0; ks < 8; ks++) {
            bf16x8 bfrag = bp[ks * 64];
            acc = __builtin_amdgcn_mfma_f32_16x16x32_bf16(afrag[ks], bfrag, acc, 0, 0, 0);
        }
        bf16x4 hv;
#pragma unroll
        for (int r = 0; r < 4; r++) hv[r] = (bf16_t)acc[r];
        xz2[((size_t)(t * 4 + w) * 64 + ntg) * 64 + lane] = hv;
    }
}

__device__ __forceinline__ float sigmoid_f(float z) {
    return 1.0f / (1.0f + __expf(-z));
}
__device__ __forceinline__ float tanh_f(float z) {
    float e = __expf(2.0f * z);
    return 1.0f - 2.0f / (e + 1.0f);
}
__device__ __forceinline__ unsigned pack2(float a, float b) {
    unsigned short xs = __builtin_bit_cast(unsigned short, (bf16_t)a);
    unsigned short ys = __builtin_bit_cast(unsigned short, (bf16_t)b);
    return (unsigned)xs | ((unsigned)ys << 16);
}
__device__ __forceinline__ bf16_t unpk_lo(unsigned v) {
    return __builtin_bit_cast(bf16_t, (unsigned short)(v & 0xffffu));
}
__device__ __forceinline__ bf16_t unpk_hi(unsigned v) {
    return __builtin_bit_cast(bf16_t, (unsigned short)(v >> 16));
}

__global__ void init_flags(unsigned* __restrict__ cnt) {
    int i = blockIdx.x * 256 + threadIdx.x;
    if (i < T_SZ * 32) cnt[i] = 0u;
}

// ---------------------------------------------------------------------------
// Phase B: recurrence. Grid: 32 blocks x 256 thr (4 waves).
// block = g*8 + u : batch group g (batches 16g..16g+16), unit slice u
// (units 32u..32u+32 = unit-tiles {u*2, u*2+1}).
// Waves 0,1: compute unit-tile tw=w (z-tiles G*16 + u*2 + tw, G=0..3),
//   B-frags from LDS-resident U-slice, gates/c/h in-register, publish own
//   16 units (2 atomic dwords/lane) + release fetch_add on cnt[t][g][u].
// Waves 2,3: for each of 7 sibling slices, acquire-spin cnt==2 then pull
//   256 dwords into next h_lds buffer (wave2: k=1..4, wave3: k=5..7).
// One __syncthreads per step; h_lds double-buffered by t&1.
// ---------------------------------------------------------------------------
__global__ __launch_bounds__(256) void lstm_lds(const bf16x4* __restrict__ xz2,
                                                const bf16_t* __restrict__ Up,
                                                unsigned* __restrict__ cnt,
                                                unsigned* __restrict__ hexch,
                                                float* __restrict__ hfin) {
    __shared__ __align__(16) bf16x8 ulds[64][64];      // 64 KB: U-slice frags
    __shared__ __align__(16) bf16_t h_lds[2][16][264]; // 16.5 KB, dbl-buffered

    const int u    = blockIdx.x & 7;
    const int g    = blockIdx.x >> 3;
    const int w    = threadIdx.x >> 6;    // 0,1 compute; 2,3 comm
    const int lane = threadIdx.x & 63;
    const int l15  = lane & 15;
    const int quad = lane >> 4;

    // ---- one-time init: U-slice -> LDS, h0 = 0 -----------------------------
    {
        const bf16x8* Ufr = (const bf16x8*)Up;
        for (int i = threadIdx.x; i < 64 * 64; i += 256) {
            int fi = i >> 6, ln = i & 63;
            int tw = (fi >> 5) & 1, G = (fi >> 3) & 3, ks = fi & 7;
            int gfrag = (G * 16 + u * 2 + tw) * 8 + ks;
            ulds[fi][ln] = Ufr[gfrag * 64 + ln];
        }
        for (int i = threadIdx.x; i < 2 * 16 * 264; i += 256)
            (&h_lds[0][0][0])[i] = (bf16_t)0.0f;
    }

    const int tw = w;                      // compute waves' unit-tile (w<2)
    f32x4 cst = {0.f, 0.f, 0.f, 0.f};      // c: batch quad*4+r, unit u*32+tw*16+l15

    bf16x4 xzv[4];
    if (w < 2) {
#pragma unroll
        for (int G = 0; G < 4; G++)
            xzv[G] = xz2[((size_t)(0 * 4 + g) * 64 + (G * 16 + u * 2 + tw)) * 64 + lane];
    }

    __syncthreads();

    for (int t = 0; t < T_SZ; t++) {
        const int buf  = t & 1;
        const int nbuf = buf ^ 1;

        if (w < 2) {
            // A-frags from current h buffer
            bf16x8 af[8];
#pragma unroll
            for (int ks = 0; ks < 8; ks++)
                af[ks] = *(const bf16x8*)&h_lds[buf][l15][ks * 32 + quad * 8];

            f32x4 acc[4];
#pragma unroll
            for (int G = 0; G < 4; G++) {
                bf16x4 xv = xzv[G];
                f32x4 a = {(float)xv[0], (float)xv[1], (float)xv[2], (float)xv[3]};
                acc[G] = a;
            }
#pragma unroll
            for (int ks = 0; ks < 8; ks++) {
#pragma unroll
                for (int G = 0; G < 4; G++) {
                    bf16x8 bfrag = ulds[(tw * 4 + G) * 8 + ks][lane];
                    acc[G] = __builtin_amdgcn_mfma_f32_16x16x32_bf16(af[ks], bfrag, acc[G], 0, 0, 0);
                }
            }

            if (t + 1 < T_SZ) {   // prefetch next step's xz
#pragma unroll
                for (int G = 0; G < 4; G++)
                    xzv[G] = xz2[((size_t)((t + 1) * 4 + g) * 64 + (G * 16 + u * 2 + tw)) * 64 + lane];
            }

            float hv[4];
#pragma unroll
            for (int r = 0; r < 4; r++) {
                float ig = sigmoid_f(acc[0][r]);
                float fg = sigmoid_f(acc[1][r]);
                float gg = tanh_f(acc[2][r]);
                float og = sigmoid_f(acc[3][r]);
                float cn = fg * cst[r] + ig * gg;
                cst[r] = cn;
                hv[r] = og * tanh_f(cn);
            }

            if (t == T_SZ - 1) {
#pragma unroll
                for (int r = 0; r < 4; r++)
                    hfin[(g * 16 + quad * 4 + r) * HID + u * 32 + tw * 16 + l15] = hv[r];
            } else {
                // own slice -> next h buffer
#pragma unroll
                for (int r = 0; r < 4; r++)
                    h_lds[nbuf][quad * 4 + r][u * 32 + tw * 16 + l15] = (bf16_t)hv[r];
                // publish 16 units for siblings
                unsigned dw0 = pack2(hv[0], hv[1]);
                unsigned dw1 = pack2(hv[2], hv[3]);
                unsigned sbase = (unsigned)(((buf * 4 + g) * 8 + u) * 256);
                unsigned di = (unsigned)(tw * 16 + l15) * 8u + (unsigned)(quad * 2);
                __hip_atomic_store(&hexch[sbase + di],     dw0, __ATOMIC_RELAXED, __HIP_MEMORY_SCOPE_AGENT);
                __hip_atomic_store(&hexch[sbase + di + 1], dw1, __ATOMIC_RELAXED, __HIP_MEMORY_SCOPE_AGENT);
                if ((threadIdx.x & 63) == 0)   // wave-level release (vmcnt drain)
                    __hip_atomic_fetch_add(&cnt[(t * 4 + g) * 8 + u], 1u,
                                           __ATOMIC_RELEASE, __HIP_MEMORY_SCOPE_AGENT);
            }
        } else if (t < T_SZ - 1) {
            // comm waves: pull sibling slices into next h buffer
            const int k0 = (w == 2) ? 1 : 5;
            const int k1 = (w == 2) ? 5 : 8;
            const int ul  = lane >> 1;
            const int bp0 = (lane & 1) * 4;
            for (int k = k0; k < k1; k++) {
                int s = (u + k) & 7;
                const unsigned* c = &cnt[(t * 4 + g) * 8 + s];
                while (__hip_atomic_load(c, __ATOMIC_ACQUIRE, __HIP_MEMORY_SCOPE_AGENT) < 2u) {}
                unsigned pbase = (unsigned)(((buf * 4 + g) * 8 + s) * 256) + (unsigned)lane * 4u;
                unsigned d[4];
#pragma unroll
                for (int j = 0; j < 4; j++)
                    d[j] = __hip_atomic_load(&hexch[pbase + j], __ATOMIC_RELAXED, __HIP_MEMORY_SCOPE_AGENT);
                int col = s * 32 + ul;
#pragma unroll
                for (int j = 0; j < 4; j++) {
                    h_lds[nbuf][2 * (bp0 + j)][col]     = unpk_lo(d[j]);
                    h_lds[nbuf][2 * (bp0 + j) + 1][col] = unpk_hi(d[j]);
                }
            }
        }

        if (t == T_SZ - 1) break;   // uniform exit, no barrier mismatch
        __syncthreads();            // next h buffer complete
    }
}

// ---------------------------------------------------------------------------
// Phase C: logits = h_T @ Wd + bd; softmax. One block per batch row.
// ---------------------------------------------------------------------------
__global__ void head(const float* __restrict__ hfin, const float* __restrict__ Wd,
                     const float* __restrict__ bd, float* __restrict__ out) {
    __shared__ float hrow[HID];
    __shared__ float lg[32];
    __shared__ float ex[32];
    int b = blockIdx.x, tid = threadIdx.x;   // 64 threads
    for (int i = tid; i < HID; i += 64) hrow[i] = hfin[b * HID + i];
    __syncthreads();
    if (tid < NCLS) {
        float acc = bd[tid];
        for (int k = 0; k < HID; k++) acc = fmaf(hrow[k], Wd[k * NCLS + tid], acc);
        lg[tid] = acc;
    }
    __syncthreads();
    if (tid < NCLS) {
        float m = -1e30f;
        for (int jj = 0; jj < NCLS; jj++) m = fmaxf(m, lg[jj]);
        ex[tid] = __expf(lg[tid] - m);
    }
    __syncthreads();
    if (tid < NCLS) {
        float sden = 0.0f;
        for (int jj = 0; jj < NCLS; jj++) sden += ex[jj];
        out[b * NCLS + tid] = ex[tid] / sden;
    }
}

// ---------------------------------------------------------------------------
extern "C" void kernel_launch(void* const* d_in, const int* in_sizes, int n_in,
                              void* d_out, int out_size, void* d_ws, size_t ws_size,
                              hipStream_t stream) {
    const int*   x    = (const int*)d_in[0];
    const float* emb  = (const float*)d_in[1];
    const float* W    = (const float*)d_in[2];
    const float* U    = (const float*)d_in[3];
    const float* bias = (const float*)d_in[4];
    const float* Wd   = (const float*)d_in[5];
    const float* bd   = (const float*)d_in[6];
    float* out = (float*)d_out;

    char* ws = (char*)d_ws;
    bf16_t*   Up    = (bf16_t*)(ws + WS_UPACK);
    bf16_t*   Wp    = (bf16_t*)(ws + WS_WPACK);
    float*    hf    = (float*)(ws + WS_HFIN);
    unsigned* cnt   = (unsigned*)(ws + WS_CNT);
    unsigned* hexch = (unsigned*)(ws + WS_HEXCH);
    bf16x4*   xz2   = (bf16x4*)(ws + WS_XZ);

    init_flags<<<dim3(64), dim3(256), 0, stream>>>(cnt);
    pack_weights<<<dim3(1024), dim3(256), 0, stream>>>(W, U, Wp, Up);
    xz_gemm<<<dim3(4096), dim3(256), 0, stream>>>(x, emb, Wp, bias, xz2);
    lstm_lds<<<dim3(32), dim3(256), 0, stream>>>(xz2, Up, cnt, hexch, hf);
    head<<<dim3(64), dim3(64), 0, stream>>>(hf, Wd, bd, out);
}

// Round 5
// 1720.722 us; speedup vs baseline: 2.3137x; 2.3137x over previous
//
#include <hip/hip_runtime.h>
#include <hip/hip_bf16.h>
#include <math.h>

// ---------------------------------------------------------------------------
// LSTM text classifier forward, MI355X/gfx950.  Round 5.
//
// R3/R4 lessons: plain-VGPR pinning of U spills to scratch (alloc cap 256
// v-regs, allocator bails); LDS-U costs ~64-128KB/step of LDS BW on the
// critical path; serial sibling spins stack L3 RTs.
//
// R5:
//  - U lives in AGPRs (gfx950 unified file; MFMA reads B from "a" class
//    directly). Pinned via asm "+a"; MFMA emitted as inline asm:
//      v_mfma_f32_16x16x32_bf16 acc(v), af(v), u(a), acc
//    Per wave: 4 gates x 8 ks = 32 frags = 128 AGPRs. ~90 VGPRs alongside
//    -> fits 2 waves/SIMD (__launch_bounds__(512,2), 256 combined cap).
//  - 8 worker blocks = 4 batch-groups x 2 halves (128 units each); the only
//    cross-CU exchange is between 2 partner blocks.
//  - Flagless handshake: producer stores {data, ~data} dword pairs (relaxed
//    agent atomics); consumer polls until mirror == ~data. Any mixed
//    stale/new state that validates implies stale bits == new bits => always
//    correct. Initial state = harness 0xAA ws-poison (0xAAAAAAAA, ~P != P).
//    Slots keyed by t%8; consumer re-poisons after consuming (producer
//    reuses 8 steps later; partner drift bound is 1 step => safe).
//  - Blocks b and b+8 partner => same XCD under %8 round-robin (speed bet
//    only); blocks with (b&4) exit (spares).
//
// MFMA 16x16x32 bf16 layouts (m89/m91):
//   A[m][k]: m=lane&15, k=(lane>>4)*8+j      B[k][n]: n=lane&15, same k
//   C/D:     col=lane&15, row=(lane>>4)*4+reg
// ---------------------------------------------------------------------------

typedef __bf16 bf16_t;
typedef bf16_t bf16x8 __attribute__((ext_vector_type(8)));
typedef bf16_t bf16x4 __attribute__((ext_vector_type(4)));
typedef float  f32x4  __attribute__((ext_vector_type(4)));

#define T_SZ 512
#define HID 256
#define G4 1024
#define NCLS 20

// workspace layout (bytes)
#define WS_UPACK 0u
#define WS_WPACK (512u * 1024u)
#define WS_HFIN  (1024u * 1024u)                  // 64 KB
#define WS_EXCH  (1536u * 1024u)                  // 512 KB: 8 slots x 4 g x 2 p x 2048 dw
#define WS_XZ    (2u * 1024u * 1024u)             // 64 MB
// total: 66 MB

// ---------------------------------------------------------------------------
// Pack W and U (f32 [256][1024]) into bf16 B-fragment order:
// frag f = (ntile*8 + kstep)*64 + lane ; element j=0..7
// value = M[kstep*32 + (lane>>4)*8 + j][ntile*16 + (lane&15)]
// ---------------------------------------------------------------------------
__global__ void pack_weights(const float* __restrict__ W, const float* __restrict__ U,
                             bf16_t* __restrict__ Wp, bf16_t* __restrict__ Up) {
    int tid  = blockIdx.x * blockDim.x + threadIdx.x;   // 0..262143
    int j    = tid & 7;
    int lane = (tid >> 3) & 63;
    int ks   = (tid >> 9) & 7;
    int nt   = tid >> 12;
    int row  = ks * 32 + ((lane >> 4) << 3) + j;
    int col  = nt * 16 + (lane & 15);
    Wp[tid] = (bf16_t)W[row * G4 + col];
    Up[tid] = (bf16_t)U[row * G4 + col];
}

// ---------------------------------------------------------------------------
// Phase A: xz = emb[x] @ W + bias, stored bf16 in C-fragment order:
//   xz2[((t*4 + bchunk)*64 + ntile)*64 + lane] = bf16x4 {r=0..3}
// value[r] = z[batch = bchunk*16 + (lane>>4)*4 + r][col = ntile*16 + (lane&15)]
// ---------------------------------------------------------------------------
__global__ __launch_bounds__(256) void xz_gemm(const int* __restrict__ x,
                                               const float* __restrict__ emb,
                                               const bf16_t* __restrict__ Wp,
                                               const float* __restrict__ bias,
                                               bf16x4* __restrict__ xz2) {
    int nb   = blockIdx.x & 7;
    int t    = blockIdx.x >> 3;
    int w    = threadIdx.x >> 6;
    int lane = threadIdx.x & 63;
    int l15  = lane & 15;
    int quad = lane >> 4;

    int b_row = w * 16 + l15;
    int tok   = x[b_row * T_SZ + t];
    const float* erow = emb + (size_t)tok * 256;

    bf16x8 afrag[8];
#pragma unroll
    for (int ks = 0; ks < 8; ks++) {
        const float4* p = (const float4*)(erow + ks * 32 + quad * 8);
        float4 v0 = p[0], v1 = p[1];
        bf16x8 a;
        a[0] = (bf16_t)v0.x; a[1] = (bf16_t)v0.y; a[2] = (bf16_t)v0.z; a[3] = (bf16_t)v0.w;
        a[4] = (bf16_t)v1.x; a[5] = (bf16_t)v1.y; a[6] = (bf16_t)v1.z; a[7] = (bf16_t)v1.w;
        afrag[ks] = a;
    }

    const bf16x8* Wf = (const bf16x8*)Wp;

#pragma unroll
    for (int nt = 0; nt < 8; nt++) {
        int ntg = nb * 8 + nt;
        float bv = bias[ntg * 16 + l15];
        f32x4 acc = {bv, bv, bv, bv};
        const bf16x8* bp = Wf + (size_t)(ntg * 8) * 64 + lane;
#pragma unroll
        for (int ks = 0; ks < 8; ks++) {
            bf16x8 bfrag = bp[ks * 64];
            acc = __builtin_amdgcn_mfma_f32_16x16x32_bf16(afrag[ks], bfrag, acc, 0, 0, 0);
        }
        bf16x4 hv;
#pragma unroll
        for (int r = 0; r < 4; r++) hv[r] = (bf16_t)acc[r];
        xz2[((size_t)(t * 4 + w) * 64 + ntg) * 64 + lane] = hv;
    }
}

__device__ __forceinline__ float sigmoid_f(float z) {
    return 1.0f / (1.0f + __expf(-z));
}
__device__ __forceinline__ float tanh_f(float z) {
    float e = __expf(2.0f * z);
    return 1.0f - 2.0f / (e + 1.0f);
}
__device__ __forceinline__ unsigned pack2(float a, float b) {
    unsigned short xs = __builtin_bit_cast(unsigned short, (bf16_t)a);
    unsigned short ys = __builtin_bit_cast(unsigned short, (bf16_t)b);
    return (unsigned)xs | ((unsigned)ys << 16);
}
__device__ __forceinline__ bf16_t unpk_lo(unsigned v) {
    return __builtin_bit_cast(bf16_t, (unsigned short)(v & 0xffffu));
}
__device__ __forceinline__ bf16_t unpk_hi(unsigned v) {
    return __builtin_bit_cast(bf16_t, (unsigned short)(v >> 16));
}

// MFMA with B operand in AGPR class (gfx950: A/B may come from AGPRs).
__device__ __forceinline__ void mfma_aB(f32x4& d, bf16x8 a, bf16x8 b) {
    asm("v_mfma_f32_16x16x32_bf16 %0, %1, %2, %0" : "+v"(d) : "v"(a), "a"(b));
}

#define POISON 0xAAAAAAAAu

// ---------------------------------------------------------------------------
// Phase B: recurrence. Grid: 16 blocks x 512 thr (8 waves); blocks with
// (b&4) exit. Worker b: group g=b&3 (batches 16g..16g+16), half p=b>>3
// (units 128p..128p+128); partner = b^8 (same XCD under %8 round-robin).
// Wave w owns unit-tile p*8+w: ureg[4][8] in AGPRs, 32 MFMAs/step, gates/
// c/h in-register. Exchange: mirrored-pair flagless handshake (see header).
// ---------------------------------------------------------------------------
__global__ __launch_bounds__(512, 2) void lstm_pair(const bf16x4* __restrict__ xz2,
                                                    const bf16_t* __restrict__ Up,
                                                    unsigned* __restrict__ exch,
                                                    float* __restrict__ hfin) {
    if (blockIdx.x & 4) return;           // spares (XCD-placement trick)
    const int g    = blockIdx.x & 3;
    const int p    = (blockIdx.x >> 3) & 1;
    const int w    = threadIdx.x >> 6;
    const int lane = threadIdx.x & 63;
    const int l15  = lane & 15;
    const int quad = lane >> 4;

    __shared__ __align__(16) bf16_t h_lds[2][16][264];

    // ---- U-slice -> AGPRs (once) -------------------------------------------
    const bf16x8* Uf = (const bf16x8*)Up + lane;
    bf16x8 u[4][8];
#pragma unroll
    for (int G = 0; G < 4; G++) {
        int ntg = G * 16 + p * 8 + w;
#pragma unroll
        for (int ks = 0; ks < 8; ks++)
            u[G][ks] = Uf[(ntg * 8 + ks) * 64];
    }
    asm volatile("" : "+a"(u[0][0]), "+a"(u[0][1]), "+a"(u[0][2]), "+a"(u[0][3]),
                      "+a"(u[0][4]), "+a"(u[0][5]), "+a"(u[0][6]), "+a"(u[0][7]));
    asm volatile("" : "+a"(u[1][0]), "+a"(u[1][1]), "+a"(u[1][2]), "+a"(u[1][3]),
                      "+a"(u[1][4]), "+a"(u[1][5]), "+a"(u[1][6]), "+a"(u[1][7]));
    asm volatile("" : "+a"(u[2][0]), "+a"(u[2][1]), "+a"(u[2][2]), "+a"(u[2][3]),
                      "+a"(u[2][4]), "+a"(u[2][5]), "+a"(u[2][6]), "+a"(u[2][7]));
    asm volatile("" : "+a"(u[3][0]), "+a"(u[3][1]), "+a"(u[3][2]), "+a"(u[3][3]),
                      "+a"(u[3][4]), "+a"(u[3][5]), "+a"(u[3][6]), "+a"(u[3][7]));

    for (int i = threadIdx.x; i < 2 * 16 * 264; i += 512)
        (&h_lds[0][0][0])[i] = (bf16_t)0.0f;      // h0 = 0 (both buffers)

    f32x4 cst = {0.f, 0.f, 0.f, 0.f};   // c: batch quad*4+r, unit p*128+w*16+l15

    bf16x4 xzv[4];
#pragma unroll
    for (int G = 0; G < 4; G++)
        xzv[G] = xz2[((size_t)(0 * 4 + g) * 64 + (G * 16 + p * 8 + w)) * 64 + lane];

    __syncthreads();

    for (int t = 0; t < T_SZ; t++) {
        const int buf  = t & 1;
        const int nbuf = buf ^ 1;

        // A-frags (full 256-unit h) from current buffer
        bf16x8 af[8];
#pragma unroll
        for (int ks = 0; ks < 8; ks++)
            af[ks] = *(const bf16x8*)&h_lds[buf][l15][ks * 32 + quad * 8];

        f32x4 acc[4];
#pragma unroll
        for (int G = 0; G < 4; G++) {
            bf16x4 xv = xzv[G];
            f32x4 a = {(float)xv[0], (float)xv[1], (float)xv[2], (float)xv[3]};
            acc[G] = a;
        }
#pragma unroll
        for (int ks = 0; ks < 8; ks++)
#pragma unroll
            for (int G = 0; G < 4; G++)
                mfma_aB(acc[G], af[ks], u[G][ks]);

        if (t + 1 < T_SZ) {   // prefetch next xz
#pragma unroll
            for (int G = 0; G < 4; G++)
                xzv[G] = xz2[((size_t)((t + 1) * 4 + g) * 64 + (G * 16 + p * 8 + w)) * 64 + lane];
        }

        float hv[4];
#pragma unroll
        for (int r = 0; r < 4; r++) {
            float ig = sigmoid_f(acc[0][r]);
            float fg = sigmoid_f(acc[1][r]);
            float gg = tanh_f(acc[2][r]);
            float og = sigmoid_f(acc[3][r]);
            float cn = fg * cst[r] + ig * gg;
            cst[r] = cn;
            hv[r] = og * tanh_f(cn);
        }

        if (t == T_SZ - 1) {   // uniform exit
#pragma unroll
            for (int r = 0; r < 4; r++)
                hfin[(g * 16 + quad * 4 + r) * HID + p * 128 + w * 16 + l15] = hv[r];
            break;
        }

        // own h -> next buffer (local half)
#pragma unroll
        for (int r = 0; r < 4; r++)
            h_lds[nbuf][quad * 4 + r][p * 128 + w * 16 + l15] = (bf16_t)hv[r];

        // publish to partner: data + complement mirror
        {
            unsigned dw0 = pack2(hv[0], hv[1]);
            unsigned dw1 = pack2(hv[2], hv[3]);
            unsigned base = (((unsigned)(t & 7) * 4 + (unsigned)g) * 2 + (unsigned)p) * 2048u;
            unsigned di   = (unsigned)(w * 16 + l15) * 8u + (unsigned)(quad * 2);
            __hip_atomic_store(&exch[base + di],          dw0,  __ATOMIC_RELAXED, __HIP_MEMORY_SCOPE_AGENT);
            __hip_atomic_store(&exch[base + di + 1],      dw1,  __ATOMIC_RELAXED, __HIP_MEMORY_SCOPE_AGENT);
            __hip_atomic_store(&exch[base + 1024 + di],     ~dw0, __ATOMIC_RELAXED, __HIP_MEMORY_SCOPE_AGENT);
            __hip_atomic_store(&exch[base + 1024 + di + 1], ~dw1, __ATOMIC_RELAXED, __HIP_MEMORY_SCOPE_AGENT);
        }

        // poll partner's half: thread handles data dwords {2*tid, 2*tid+1}
        {
            unsigned pbase = (((unsigned)(t & 7) * 4 + (unsigned)g) * 2 + (unsigned)(1 - p)) * 2048u;
            unsigned i0 = (unsigned)threadIdx.x * 2u;
            unsigned d0, d1, m0, m1;
            for (;;) {
                d0 = __hip_atomic_load(&exch[pbase + i0],          __ATOMIC_RELAXED, __HIP_MEMORY_SCOPE_AGENT);
                d1 = __hip_atomic_load(&exch[pbase + i0 + 1],      __ATOMIC_RELAXED, __HIP_MEMORY_SCOPE_AGENT);
                m0 = __hip_atomic_load(&exch[pbase + 1024 + i0],   __ATOMIC_RELAXED, __HIP_MEMORY_SCOPE_AGENT);
                m1 = __hip_atomic_load(&exch[pbase + 1024 + i0 + 1], __ATOMIC_RELAXED, __HIP_MEMORY_SCOPE_AGENT);
                if ((m0 == ~d0) && (m1 == ~d1)) break;
            }
            // re-poison for reuse at t+8
            __hip_atomic_store(&exch[pbase + i0],            POISON, __ATOMIC_RELAXED, __HIP_MEMORY_SCOPE_AGENT);
            __hip_atomic_store(&exch[pbase + i0 + 1],        POISON, __ATOMIC_RELAXED, __HIP_MEMORY_SCOPE_AGENT);
            __hip_atomic_store(&exch[pbase + 1024 + i0],     POISON, __ATOMIC_RELAXED, __HIP_MEMORY_SCOPE_AGENT);
            __hip_atomic_store(&exch[pbase + 1024 + i0 + 1], POISON, __ATOMIC_RELAXED, __HIP_MEMORY_SCOPE_AGENT);
            // scatter into next buffer: lu = unit, qq = quad, dwords = batch pairs
            int lu = (int)(i0 >> 3);
            int qq = (int)((i0 & 7) >> 1);
            int col = (1 - p) * 128 + lu;
            h_lds[nbuf][qq * 4 + 0][col] = unpk_lo(d0);
            h_lds[nbuf][qq * 4 + 1][col] = unpk_hi(d0);
            h_lds[nbuf][qq * 4 + 2][col] = unpk_lo(d1);
            h_lds[nbuf][qq * 4 + 3][col] = unpk_hi(d1);
        }

        __syncthreads();   // next h buffer complete
    }
}

// ---------------------------------------------------------------------------
// Phase C: logits = h_T @ Wd + bd; softmax. One block per batch row.
// ---------------------------------------------------------------------------
__global__ void head(const float* __restrict__ hfin, const float* __restrict__ Wd,
                     const float* __restrict__ bd, float* __restrict__ out) {
    __shared__ float hrow[HID];
    __shared__ float lg[32];
    __shared__ float ex[32];
    int b = blockIdx.x, tid = threadIdx.x;   // 64 threads
    for (int i = tid; i < HID; i += 64) hrow[i] = hfin[b * HID + i];
    __syncthreads();
    if (tid < NCLS) {
        float acc = bd[tid];
        for (int k = 0; k < HID; k++) acc = fmaf(hrow[k], Wd[k * NCLS + tid], acc);
        lg[tid] = acc;
    }
    __syncthreads();
    if (tid < NCLS) {
        float m = -1e30f;
        for (int jj = 0; jj < NCLS; jj++) m = fmaxf(m, lg[jj]);
        ex[tid] = __expf(lg[tid] - m);
    }
    __syncthreads();
    if (tid < NCLS) {
        float sden = 0.0f;
        for (int jj = 0; jj < NCLS; jj++) sden += ex[jj];
        out[b * NCLS + tid] = ex[tid] / sden;
    }
}

// ---------------------------------------------------------------------------
extern "C" void kernel_launch(void* const* d_in, const int* in_sizes, int n_in,
                              void* d_out, int out_size, void* d_ws, size_t ws_size,
                              hipStream_t stream) {
    const int*   x    = (const int*)d_in[0];
    const float* emb  = (const float*)d_in[1];
    const float* W    = (const float*)d_in[2];
    const float* U    = (const float*)d_in[3];
    const float* bias = (const float*)d_in[4];
    const float* Wd   = (const float*)d_in[5];
    const float* bd   = (const float*)d_in[6];
    float* out = (float*)d_out;

    char* ws = (char*)d_ws;
    bf16_t*   Up   = (bf16_t*)(ws + WS_UPACK);
    bf16_t*   Wp   = (bf16_t*)(ws + WS_WPACK);
    float*    hf   = (float*)(ws + WS_HFIN);
    unsigned* exch = (unsigned*)(ws + WS_EXCH);
    bf16x4*   xz2  = (bf16x4*)(ws + WS_XZ);

    pack_weights<<<dim3(1024), dim3(256), 0, stream>>>(W, U, Wp, Up);
    xz_gemm<<<dim3(4096), dim3(256), 0, stream>>>(x, emb, Wp, bias, xz2);
    lstm_pair<<<dim3(16), dim3(512), 0, stream>>>(xz2, Up, exch, hf);
    head<<<dim3(64), dim3(64), 0, stream>>>(hf, Wd, bd, out);
}

// Round 6
// 1458.025 us; speedup vs baseline: 2.7305x; 1.1802x over previous
//
#include <hip/hip_runtime.h>
#include <hip/hip_bf16.h>
#include <math.h>

// ---------------------------------------------------------------------------
// LSTM text classifier forward, MI355X/gfx950.  Round 6.
//
// R5 post-mortem: AGPR-resident U works (1560us; VGPR=92+128acc, no spill).
// Remaining 2.7us/step = handshake: per-dword agent atomics (publish+poison
// +poll) -> WRITE_SIZE 131MB, L3 contention, vmcnt(0) store-ack drains.
//
// R6: same pair structure, 4x cheaper handshake:
//  - Epoch-keyed mirror: mirror = data ^ key, key=((t>>3)+1)<<24. Ring slot
//    t%8. Stale generations and harness 0xAA poison can never validate
//    (keys differ / key!=0) -> NO re-poison pass, no init kernel.
//  - 64-bit atomics: one u64 = {data dword, data^key}; publish = 2 stores,
//    poll = 2 loads per thread. 4x fewer coherent ops, half the volume.
//  - Publish fired immediately after h computed (prop starts earlier).
//  - Drift safety: blocks mutually sync each step => when producer reuses
//    slot t%8 at t+8, partner consumed slot t at least 6 steps ago.
//
// Structure recap (R5): 8 worker blocks = 4 batch-groups x 2 halves
// (128 units); U in AGPRs via "+a" pin + inline-asm MFMA (B from AGPR);
// h double-buffered in LDS; partner blocks b,b^8 (same XCD under %8 rr;
// blocks with b&4 exit as spares).
//
// MFMA 16x16x32 bf16 layouts (m89/m91):
//   A[m][k]: m=lane&15, k=(lane>>4)*8+j      B[k][n]: n=lane&15, same k
//   C/D:     col=lane&15, row=(lane>>4)*4+reg
// ---------------------------------------------------------------------------

typedef __bf16 bf16_t;
typedef bf16_t bf16x8 __attribute__((ext_vector_type(8)));
typedef bf16_t bf16x4 __attribute__((ext_vector_type(4)));
typedef float  f32x4  __attribute__((ext_vector_type(4)));
typedef unsigned long long u64;

#define T_SZ 512
#define HID 256
#define G4 1024
#define NCLS 20

// workspace layout (bytes)
#define WS_UPACK 0u
#define WS_WPACK (512u * 1024u)
#define WS_HFIN  (1024u * 1024u)                  // 64 KB
#define WS_EXCH  (1536u * 1024u)                  // 512 KB: 8 slots x 4g x 2p x 1024 u64
#define WS_XZ    (2u * 1024u * 1024u)             // 64 MB
// total: 66 MB

// ---------------------------------------------------------------------------
// Pack W and U (f32 [256][1024]) into bf16 B-fragment order:
// frag f = (ntile*8 + kstep)*64 + lane ; element j=0..7
// value = M[kstep*32 + (lane>>4)*8 + j][ntile*16 + (lane&15)]
// ---------------------------------------------------------------------------
__global__ void pack_weights(const float* __restrict__ W, const float* __restrict__ U,
                             bf16_t* __restrict__ Wp, bf16_t* __restrict__ Up) {
    int tid  = blockIdx.x * blockDim.x + threadIdx.x;   // 0..262143
    int j    = tid & 7;
    int lane = (tid >> 3) & 63;
    int ks   = (tid >> 9) & 7;
    int nt   = tid >> 12;
    int row  = ks * 32 + ((lane >> 4) << 3) + j;
    int col  = nt * 16 + (lane & 15);
    Wp[tid] = (bf16_t)W[row * G4 + col];
    Up[tid] = (bf16_t)U[row * G4 + col];
}

// ---------------------------------------------------------------------------
// Phase A: xz = emb[x] @ W + bias, stored bf16 in C-fragment order:
//   xz2[((t*4 + bchunk)*64 + ntile)*64 + lane] = bf16x4 {r=0..3}
// value[r] = z[batch = bchunk*16 + (lane>>4)*4 + r][col = ntile*16 + (lane&15)]
// ---------------------------------------------------------------------------
__global__ __launch_bounds__(256) void xz_gemm(const int* __restrict__ x,
                                               const float* __restrict__ emb,
                                               const bf16_t* __restrict__ Wp,
                                               const float* __restrict__ bias,
                                               bf16x4* __restrict__ xz2) {
    int nb   = blockIdx.x & 7;
    int t    = blockIdx.x >> 3;
    int w    = threadIdx.x >> 6;
    int lane = threadIdx.x & 63;
    int l15  = lane & 15;
    int quad = lane >> 4;

    int b_row = w * 16 + l15;
    int tok   = x[b_row * T_SZ + t];
    const float* erow = emb + (size_t)tok * 256;

    bf16x8 afrag[8];
#pragma unroll
    for (int ks = 0; ks < 8; ks++) {
        const float4* p = (const float4*)(erow + ks * 32 + quad * 8);
        float4 v0 = p[0], v1 = p[1];
        bf16x8 a;
        a[0] = (bf16_t)v0.x; a[1] = (bf16_t)v0.y; a[2] = (bf16_t)v0.z; a[3] = (bf16_t)v0.w;
        a[4] = (bf16_t)v1.x; a[5] = (bf16_t)v1.y; a[6] = (bf16_t)v1.z; a[7] = (bf16_t)v1.w;
        afrag[ks] = a;
    }

    const bf16x8* Wf = (const bf16x8*)Wp;

#pragma unroll
    for (int nt = 0; nt < 8; nt++) {
        int ntg = nb * 8 + nt;
        float bv = bias[ntg * 16 + l15];
        f32x4 acc = {bv, bv, bv, bv};
        const bf16x8* bp = Wf + (size_t)(ntg * 8) * 64 + lane;
#pragma unroll
        for (int ks = 0; ks < 8; ks++) {
            bf16x8 bfrag = bp[ks * 64];
            acc = __builtin_amdgcn_mfma_f32_16x16x32_bf16(afrag[ks], bfrag, acc, 0, 0, 0);
        }
        bf16x4 hv;
#pragma unroll
        for (int r = 0; r < 4; r++) hv[r] = (bf16_t)acc[r];
        xz2[((size_t)(t * 4 + w) * 64 + ntg) * 64 + lane] = hv;
    }
}

__device__ __forceinline__ float sigmoid_f(float z) {
    return 1.0f / (1.0f + __expf(-z));
}
__device__ __forceinline__ float tanh_f(float z) {
    float e = __expf(2.0f * z);
    return 1.0f - 2.0f / (e + 1.0f);
}
__device__ __forceinline__ unsigned pack2(float a, float b) {
    unsigned short xs = __builtin_bit_cast(unsigned short, (bf16_t)a);
    unsigned short ys = __builtin_bit_cast(unsigned short, (bf16_t)b);
    return (unsigned)xs | ((unsigned)ys << 16);
}
__device__ __forceinline__ bf16_t unpk_lo(unsigned v) {
    return __builtin_bit_cast(bf16_t, (unsigned short)(v & 0xffffu));
}
__device__ __forceinline__ bf16_t unpk_hi(unsigned v) {
    return __builtin_bit_cast(bf16_t, (unsigned short)(v >> 16));
}

// MFMA with B operand in AGPR class (gfx950: A/B may come from AGPRs).
__device__ __forceinline__ void mfma_aB(f32x4& d, bf16x8 a, bf16x8 b) {
    asm("v_mfma_f32_16x16x32_bf16 %0, %1, %2, %0" : "+v"(d) : "v"(a), "a"(b));
}

// ---------------------------------------------------------------------------
// Phase B: recurrence. Grid: 16 blocks x 512 thr (8 waves); blocks with
// (b&4) exit. Worker b: group g=b&3 (batches 16g..16g+16), half p=b>>3
// (units 128p..128p+128); partner = b^8. Wave w owns unit-tile p*8+w:
// ureg[4][8] in AGPRs, 32 MFMAs/step, gates/c/h in-register.
// Exchange: epoch-keyed u64 {data, data^key} handshake (see header).
// ---------------------------------------------------------------------------
__global__ __launch_bounds__(512, 2) void lstm_pair(const bf16x4* __restrict__ xz2,
                                                    const bf16_t* __restrict__ Up,
                                                    u64* __restrict__ exch,
                                                    float* __restrict__ hfin) {
    if (blockIdx.x & 4) return;           // spares (XCD-placement trick)
    const int g    = blockIdx.x & 3;
    const int p    = (blockIdx.x >> 3) & 1;
    const int w    = threadIdx.x >> 6;
    const int lane = threadIdx.x & 63;
    const int l15  = lane & 15;
    const int quad = lane >> 4;

    __shared__ __align__(16) bf16_t h_lds[2][16][264];

    // ---- U-slice -> AGPRs (once) -------------------------------------------
    const bf16x8* Uf = (const bf16x8*)Up + lane;
    bf16x8 u[4][8];
#pragma unroll
    for (int G = 0; G < 4; G++) {
        int ntg = G * 16 + p * 8 + w;
#pragma unroll
        for (int ks = 0; ks < 8; ks++)
            u[G][ks] = Uf[(ntg * 8 + ks) * 64];
    }
    asm volatile("" : "+a"(u[0][0]), "+a"(u[0][1]), "+a"(u[0][2]), "+a"(u[0][3]),
                      "+a"(u[0][4]), "+a"(u[0][5]), "+a"(u[0][6]), "+a"(u[0][7]));
    asm volatile("" : "+a"(u[1][0]), "+a"(u[1][1]), "+a"(u[1][2]), "+a"(u[1][3]),
                      "+a"(u[1][4]), "+a"(u[1][5]), "+a"(u[1][6]), "+a"(u[1][7]));
    asm volatile("" : "+a"(u[2][0]), "+a"(u[2][1]), "+a"(u[2][2]), "+a"(u[2][3]),
                      "+a"(u[2][4]), "+a"(u[2][5]), "+a"(u[2][6]), "+a"(u[2][7]));
    asm volatile("" : "+a"(u[3][0]), "+a"(u[3][1]), "+a"(u[3][2]), "+a"(u[3][3]),
                      "+a"(u[3][4]), "+a"(u[3][5]), "+a"(u[3][6]), "+a"(u[3][7]));

    for (int i = threadIdx.x; i < 2 * 16 * 264; i += 512)
        (&h_lds[0][0][0])[i] = (bf16_t)0.0f;      // h0 = 0 (both buffers)

    f32x4 cst = {0.f, 0.f, 0.f, 0.f};   // c: batch quad*4+r, unit p*128+w*16+l15

    bf16x4 xzv[4];
#pragma unroll
    for (int G = 0; G < 4; G++)
        xzv[G] = xz2[((size_t)(0 * 4 + g) * 64 + (G * 16 + p * 8 + w)) * 64 + lane];

    __syncthreads();

    for (int t = 0; t < T_SZ; t++) {
        const int buf  = t & 1;
        const int nbuf = buf ^ 1;
        const unsigned key = ((unsigned)(t >> 3) + 1u) << 24;   // epoch key != 0

        // A-frags (full 256-unit h) from current buffer
        bf16x8 af[8];
#pragma unroll
        for (int ks = 0; ks < 8; ks++)
            af[ks] = *(const bf16x8*)&h_lds[buf][l15][ks * 32 + quad * 8];

        f32x4 acc[4];
#pragma unroll
        for (int G = 0; G < 4; G++) {
            bf16x4 xv = xzv[G];
            f32x4 a = {(float)xv[0], (float)xv[1], (float)xv[2], (float)xv[3]};
            acc[G] = a;
        }
#pragma unroll
        for (int ks = 0; ks < 8; ks++)
#pragma unroll
            for (int G = 0; G < 4; G++)
                mfma_aB(acc[G], af[ks], u[G][ks]);

        if (t + 1 < T_SZ) {   // prefetch next xz
#pragma unroll
            for (int G = 0; G < 4; G++)
                xzv[G] = xz2[((size_t)((t + 1) * 4 + g) * 64 + (G * 16 + p * 8 + w)) * 64 + lane];
        }

        float hv[4];
#pragma unroll
        for (int r = 0; r < 4; r++) {
            float ig = sigmoid_f(acc[0][r]);
            float fg = sigmoid_f(acc[1][r]);
            float gg = tanh_f(acc[2][r]);
            float og = sigmoid_f(acc[3][r]);
            float cn = fg * cst[r] + ig * gg;
            cst[r] = cn;
            hv[r] = og * tanh_f(cn);
        }

        if (t == T_SZ - 1) {   // uniform exit
#pragma unroll
            for (int r = 0; r < 4; r++)
                hfin[(g * 16 + quad * 4 + r) * HID + p * 128 + w * 16 + l15] = hv[r];
            break;
        }

        // publish FIRST (start propagation), then local LDS write
        {
            unsigned dw0 = pack2(hv[0], hv[1]);
            unsigned dw1 = pack2(hv[2], hv[3]);
            u64 q0 = (u64)dw0 | ((u64)(dw0 ^ key) << 32);
            u64 q1 = (u64)dw1 | ((u64)(dw1 ^ key) << 32);
            unsigned base = (((unsigned)(t & 7) * 4 + (unsigned)g) * 2 + (unsigned)p) * 1024u;
            unsigned ui   = (unsigned)(w * 16 + l15) * 8u + (unsigned)(quad * 2);
            __hip_atomic_store(&exch[base + ui],     q0, __ATOMIC_RELAXED, __HIP_MEMORY_SCOPE_AGENT);
            __hip_atomic_store(&exch[base + ui + 1], q1, __ATOMIC_RELAXED, __HIP_MEMORY_SCOPE_AGENT);
        }

#pragma unroll
        for (int r = 0; r < 4; r++)
            h_lds[nbuf][quad * 4 + r][p * 128 + w * 16 + l15] = (bf16_t)hv[r];

        // poll partner's half: thread handles u64s {2*tid, 2*tid+1}
        {
            unsigned pbase = (((unsigned)(t & 7) * 4 + (unsigned)g) * 2 + (unsigned)(1 - p)) * 1024u;
            unsigned i0 = (unsigned)threadIdx.x * 2u;
            u64 q0, q1;
            for (;;) {
                q0 = __hip_atomic_load(&exch[pbase + i0],     __ATOMIC_RELAXED, __HIP_MEMORY_SCOPE_AGENT);
                q1 = __hip_atomic_load(&exch[pbase + i0 + 1], __ATOMIC_RELAXED, __HIP_MEMORY_SCOPE_AGENT);
                bool v0 = ((unsigned)(q0 >> 32)) == (((unsigned)q0) ^ key);
                bool v1 = ((unsigned)(q1 >> 32)) == (((unsigned)q1) ^ key);
                if (v0 && v1) break;
            }
            unsigned d0 = (unsigned)q0, d1 = (unsigned)q1;
            // i0 -> unit ul=i0>>3, qq=(i0&7)>>1; i0 even: d0 = batches qq*4+{0,1},
            // d1 = batches qq*4+{2,3} (same ul, qq)
            int ul  = (int)(i0 >> 3);
            int qq  = (int)((i0 & 7) >> 1);
            int col = (1 - p) * 128 + ul;
            h_lds[nbuf][qq * 4 + 0][col] = unpk_lo(d0);
            h_lds[nbuf][qq * 4 + 1][col] = unpk_hi(d0);
            h_lds[nbuf][qq * 4 + 2][col] = unpk_lo(d1);
            h_lds[nbuf][qq * 4 + 3][col] = unpk_hi(d1);
        }

        __syncthreads();   // next h buffer complete
    }
}

// ---------------------------------------------------------------------------
// Phase C: logits = h_T @ Wd + bd; softmax. One block per batch row.
// ---------------------------------------------------------------------------
__global__ void head(const float* __restrict__ hfin, const float* __restrict__ Wd,
                     const float* __restrict__ bd, float* __restrict__ out) {
    __shared__ float hrow[HID];
    __shared__ float lg[32];
    __shared__ float ex[32];
    int b = blockIdx.x, tid = threadIdx.x;   // 64 threads
    for (int i = tid; i < HID; i += 64) hrow[i] = hfin[b * HID + i];
    __syncthreads();
    if (tid < NCLS) {
        float acc = bd[tid];
        for (int k = 0; k < HID; k++) acc = fmaf(hrow[k], Wd[k * NCLS + tid], acc);
        lg[tid] = acc;
    }
    __syncthreads();
    if (tid < NCLS) {
        float m = -1e30f;
        for (int jj = 0; jj < NCLS; jj++) m = fmaxf(m, lg[jj]);
        ex[tid] = __expf(lg[tid] - m);
    }
    __syncthreads();
    if (tid < NCLS) {
        float sden = 0.0f;
        for (int jj = 0; jj < NCLS; jj++) sden += ex[jj];
        out[b * NCLS + tid] = ex[tid] / sden;
    }
}

// ---------------------------------------------------------------------------
extern "C" void kernel_launch(void* const* d_in, const int* in_sizes, int n_in,
                              void* d_out, int out_size, void* d_ws, size_t ws_size,
                              hipStream_t stream) {
    const int*   x    = (const int*)d_in[0];
    const float* emb  = (const float*)d_in[1];
    const float* W    = (const float*)d_in[2];
    const float* U    = (const float*)d_in[3];
    const float* bias = (const float*)d_in[4];
    const float* Wd   = (const float*)d_in[5];
    const float* bd   = (const float*)d_in[6];
    float* out = (float*)d_out;

    char* ws = (char*)d_ws;
    bf16_t* Up   = (bf16_t*)(ws + WS_UPACK);
    bf16_t* Wp   = (bf16_t*)(ws + WS_WPACK);
    float*  hf   = (float*)(ws + WS_HFIN);
    u64*    exch = (u64*)(ws + WS_EXCH);
    bf16x4* xz2  = (bf16x4*)(ws + WS_XZ);

    pack_weights<<<dim3(1024), dim3(256), 0, stream>>>(W, U, Wp, Up);
    xz_gemm<<<dim3(4096), dim3(256), 0, stream>>>(x, emb, Wp, bias, xz2);
    lstm_pair<<<dim3(16), dim3(512), 0, stream>>>(xz2, Up, exch, hf);
    head<<<dim3(64), dim3(64), 0, stream>>>(hf, Wd, bd, out);
}